// Round 2
// baseline (663.790 us; speedup 1.0000x reference)
//
#include <hip/hip_runtime.h>
#include <hip/hip_bf16.h>

#define NN 50000
#define EE 800000
#define DD 128

typedef __attribute__((ext_vector_type(8))) short bf16x8;
typedef __attribute__((ext_vector_type(4))) float f32x4;

__device__ __forceinline__ short f2bf(float f) {
    __hip_bfloat16 h = __float2bfloat16(f);
    return __builtin_bit_cast(short, h);
}

__device__ __forceinline__ float fast_silu(float x) {
    return x / (1.0f + __expf(-x));
}

// ---- prep: h (fp32) -> bf16, 4 elems/thread ----
__global__ void pack_h_kernel(const float* __restrict__ h, unsigned short* __restrict__ hp) {
    int t = blockIdx.x * blockDim.x + threadIdx.x;   // 1.6M threads exactly
    float4 v = ((const float4*)h)[t];
    ushort4 o;
    o.x = (unsigned short)f2bf(v.x);
    o.y = (unsigned short)f2bf(v.y);
    o.z = (unsigned short)f2bf(v.z);
    o.w = (unsigned short)f2bf(v.w);
    ((ushort4*)hp)[t] = o;
}

// ---- prep: pack 6 128x128 weight blocks into MFMA B-fragment order ----
// pack[mat][ (nt*4+ks)*64 + lane ][j] = W[n = nt*16 + (lane&15)][k = ks*32 + (lane>>4)*8 + j]
__global__ void pack_w_kernel(const float* __restrict__ W1, const float* __restrict__ W2,
                              const float* __restrict__ U1, const float* __restrict__ U2,
                              unsigned short* __restrict__ packs) {
    int t = blockIdx.x * blockDim.x + threadIdx.x;   // 6*16384 = 98304 exactly
    int mat = t >> 14;
    int r = t & 16383;
    int j = r & 7;
    int lane = (r >> 3) & 63;
    int f = r >> 9;            // 0..31
    int ks = f & 3, nt = f >> 2;
    int n = nt * 16 + (lane & 15);
    int k = ks * 32 + (lane >> 4) * 8 + j;
    float v;
    switch (mat) {
        case 0: v = W1[n * 257 + k];        break;  // W1a (vs h_sender)
        case 1: v = W1[n * 257 + 128 + k];  break;  // W1b (vs h_receiver)
        case 2: v = W2[n * 128 + k];        break;  // W2
        case 3: v = U1[n * 256 + k];        break;  // U1a (vs h)
        case 4: v = U1[n * 256 + 128 + k];  break;  // U1b (vs agg)
        default: v = U2[n * 128 + k];       break;  // U2
    }
    packs[t] = (unsigned short)f2bf(v);
}

// ---- edge kernel: 256 threads = 4 waves, 64 edges/wave (4 M-tiles of 16) ----
__global__ __launch_bounds__(256, 2) void edge_kernel(
    const unsigned short* __restrict__ hp,     // bf16 h [NN][128]
    const float* __restrict__ coords,          // [NN][3]
    const int* __restrict__ ei,                // [2][EE] int32 (harness converts int64 -> int32)
    const bf16x8* __restrict__ w1a_pack,
    const bf16x8* __restrict__ w1b_pack,
    const bf16x8* __restrict__ w2_pack,
    const float* __restrict__ W1raw,           // for w1c = W1[d][256]
    const float* __restrict__ b1,
    const float* __restrict__ b2,
    float* __restrict__ agg)
{
    __shared__ int send_s[4][64];
    __shared__ int recv_s[4][64];
    __shared__ float dist_s[4][64];
    __shared__ unsigned short m1s[4][64][136];   // row stride 136 bf16 = 272B (16B-aligned)

    const int tid = threadIdx.x;
    const int wave = tid >> 6, lane = tid & 63;
    const int quad = lane >> 4, l15 = lane & 15;
    const int ebase = blockIdx.x * 256 + wave * 64;

    {
        int e = ebase + lane;
        int s = ei[e];
        int r = ei[EE + e];
        send_s[wave][lane] = s;
        recv_s[wave][lane] = r;
        float dx = coords[3 * s + 0] - coords[3 * r + 0];
        float dy = coords[3 * s + 1] - coords[3 * r + 1];
        float dz = coords[3 * s + 2] - coords[3 * r + 2];
        dist_s[wave][lane] = sqrtf(dx * dx + dy * dy + dz * dz);
    }
    __syncthreads();

    int srow[4], rrow[4];
    #pragma unroll
    for (int m = 0; m < 4; m++) {
        srow[m] = send_s[wave][m * 16 + l15];
        rrow[m] = recv_s[wave][m * 16 + l15];
    }

    // ---- layer 1: acc = Hs*W1a^T + Hr*W1b^T ----
    f32x4 acc[4][8];
    #pragma unroll
    for (int m = 0; m < 4; m++)
        #pragma unroll
        for (int nt = 0; nt < 8; nt++)
            acc[m][nt] = f32x4{0.f, 0.f, 0.f, 0.f};

    #pragma unroll
    for (int ks = 0; ks < 4; ks++) {
        bf16x8 a_s[4], a_r[4];
        #pragma unroll
        for (int m = 0; m < 4; m++) {
            a_s[m] = *(const bf16x8*)(hp + (size_t)srow[m] * DD + ks * 32 + quad * 8);
            a_r[m] = *(const bf16x8*)(hp + (size_t)rrow[m] * DD + ks * 32 + quad * 8);
        }
        #pragma unroll
        for (int nt = 0; nt < 8; nt++) {
            bf16x8 b = w1a_pack[(nt * 4 + ks) * 64 + lane];
            #pragma unroll
            for (int m = 0; m < 4; m++)
                acc[m][nt] = __builtin_amdgcn_mfma_f32_16x16x32_bf16(a_s[m], b, acc[m][nt], 0, 0, 0);
        }
        #pragma unroll
        for (int nt = 0; nt < 8; nt++) {
            bf16x8 b = w1b_pack[(nt * 4 + ks) * 64 + lane];
            #pragma unroll
            for (int m = 0; m < 4; m++)
                acc[m][nt] = __builtin_amdgcn_mfma_f32_16x16x32_bf16(a_r[m], b, acc[m][nt], 0, 0, 0);
        }
    }

    // ---- epilogue 1: + dist*w1c + b1, silu, -> LDS (bf16, A-layout rows) ----
    #pragma unroll
    for (int m = 0; m < 4; m++) {
        float dd[4];
        #pragma unroll
        for (int r = 0; r < 4; r++) dd[r] = dist_s[wave][m * 16 + quad * 4 + r];
        #pragma unroll
        for (int nt = 0; nt < 8; nt++) {
            int d = nt * 16 + l15;
            float w1cv = W1raw[d * 257 + 256];
            float b1v = b1[d];
            #pragma unroll
            for (int r = 0; r < 4; r++) {
                float pre = acc[m][nt][r] + dd[r] * w1cv + b1v;
                m1s[wave][m * 16 + quad * 4 + r][d] = (unsigned short)f2bf(fast_silu(pre));
            }
        }
    }
    asm volatile("s_waitcnt lgkmcnt(0)" ::: "memory");  // per-wave LDS write->read ordering

    // ---- layer 2: acc2 = M1*W2^T ----
    f32x4 acc2[4][8];
    #pragma unroll
    for (int m = 0; m < 4; m++)
        #pragma unroll
        for (int nt = 0; nt < 8; nt++)
            acc2[m][nt] = f32x4{0.f, 0.f, 0.f, 0.f};

    #pragma unroll
    for (int ks = 0; ks < 4; ks++) {
        bf16x8 a2[4];
        #pragma unroll
        for (int m = 0; m < 4; m++)
            a2[m] = *(const bf16x8*)(&m1s[wave][m * 16 + l15][ks * 32 + quad * 8]);
        #pragma unroll
        for (int nt = 0; nt < 8; nt++) {
            bf16x8 b = w2_pack[(nt * 4 + ks) * 64 + lane];
            #pragma unroll
            for (int m = 0; m < 4; m++)
                acc2[m][nt] = __builtin_amdgcn_mfma_f32_16x16x32_bf16(a2[m], b, acc2[m][nt], 0, 0, 0);
        }
    }

    // ---- epilogue 2: silu(acc2 + b2), atomic scatter-add into agg ----
    #pragma unroll
    for (int m = 0; m < 4; m++) {
        int rr[4];
        #pragma unroll
        for (int r = 0; r < 4; r++) rr[r] = recv_s[wave][m * 16 + quad * 4 + r];
        #pragma unroll
        for (int nt = 0; nt < 8; nt++) {
            int d = nt * 16 + l15;
            float b2v = b2[d];
            #pragma unroll
            for (int r = 0; r < 4; r++) {
                float v = fast_silu(acc2[m][nt][r] + b2v);
                unsafeAtomicAdd(&agg[(size_t)rr[r] * DD + d], v);
            }
        }
    }
}

// ---- node kernel: out = h + U2*silu(U1a*h + U1b*agg + c1) + c2 ----
__global__ __launch_bounds__(256, 2) void node_kernel(
    const unsigned short* __restrict__ hp,
    const float* __restrict__ hf,
    const float* __restrict__ agg,
    const bf16x8* __restrict__ u1a_pack,
    const bf16x8* __restrict__ u1b_pack,
    const bf16x8* __restrict__ u2_pack,
    const float* __restrict__ c1,
    const float* __restrict__ c2,
    float* __restrict__ out)
{
    __shared__ unsigned short u1s[4][64][136];

    const int tid = threadIdx.x;
    const int wave = tid >> 6, lane = tid & 63;
    const int quad = lane >> 4, l15 = lane & 15;
    const int nbase = blockIdx.x * 256 + wave * 64;

    int nrow[4];
    #pragma unroll
    for (int m = 0; m < 4; m++) {
        int n = nbase + m * 16 + l15;
        nrow[m] = n < NN ? n : NN - 1;
    }

    f32x4 acc[4][8];
    #pragma unroll
    for (int m = 0; m < 4; m++)
        #pragma unroll
        for (int nt = 0; nt < 8; nt++)
            acc[m][nt] = f32x4{0.f, 0.f, 0.f, 0.f};

    #pragma unroll
    for (int ks = 0; ks < 4; ks++) {
        bf16x8 ah[4], ag[4];
        #pragma unroll
        for (int m = 0; m < 4; m++) {
            ah[m] = *(const bf16x8*)(hp + (size_t)nrow[m] * DD + ks * 32 + quad * 8);
            const float* ap = agg + (size_t)nrow[m] * DD + ks * 32 + quad * 8;
            f32x4 g0 = *(const f32x4*)ap;
            f32x4 g1 = *(const f32x4*)(ap + 4);
            bf16x8 t;
            t[0] = f2bf(g0[0]); t[1] = f2bf(g0[1]); t[2] = f2bf(g0[2]); t[3] = f2bf(g0[3]);
            t[4] = f2bf(g1[0]); t[5] = f2bf(g1[1]); t[6] = f2bf(g1[2]); t[7] = f2bf(g1[3]);
            ag[m] = t;
        }
        #pragma unroll
        for (int nt = 0; nt < 8; nt++) {
            bf16x8 b = u1a_pack[(nt * 4 + ks) * 64 + lane];
            #pragma unroll
            for (int m = 0; m < 4; m++)
                acc[m][nt] = __builtin_amdgcn_mfma_f32_16x16x32_bf16(ah[m], b, acc[m][nt], 0, 0, 0);
        }
        #pragma unroll
        for (int nt = 0; nt < 8; nt++) {
            bf16x8 b = u1b_pack[(nt * 4 + ks) * 64 + lane];
            #pragma unroll
            for (int m = 0; m < 4; m++)
                acc[m][nt] = __builtin_amdgcn_mfma_f32_16x16x32_bf16(ag[m], b, acc[m][nt], 0, 0, 0);
        }
    }

    #pragma unroll
    for (int m = 0; m < 4; m++) {
        #pragma unroll
        for (int nt = 0; nt < 8; nt++) {
            int d = nt * 16 + l15;
            float c1v = c1[d];
            #pragma unroll
            for (int r = 0; r < 4; r++) {
                float pre = acc[m][nt][r] + c1v;
                u1s[wave][m * 16 + quad * 4 + r][d] = (unsigned short)f2bf(fast_silu(pre));
            }
        }
    }
    asm volatile("s_waitcnt lgkmcnt(0)" ::: "memory");

    f32x4 acc2[4][8];
    #pragma unroll
    for (int m = 0; m < 4; m++)
        #pragma unroll
        for (int nt = 0; nt < 8; nt++)
            acc2[m][nt] = f32x4{0.f, 0.f, 0.f, 0.f};

    #pragma unroll
    for (int ks = 0; ks < 4; ks++) {
        bf16x8 a2[4];
        #pragma unroll
        for (int m = 0; m < 4; m++)
            a2[m] = *(const bf16x8*)(&u1s[wave][m * 16 + l15][ks * 32 + quad * 8]);
        #pragma unroll
        for (int nt = 0; nt < 8; nt++) {
            bf16x8 b = u2_pack[(nt * 4 + ks) * 64 + lane];
            #pragma unroll
            for (int m = 0; m < 4; m++)
                acc2[m][nt] = __builtin_amdgcn_mfma_f32_16x16x32_bf16(a2[m], b, acc2[m][nt], 0, 0, 0);
        }
    }

    #pragma unroll
    for (int m = 0; m < 4; m++) {
        #pragma unroll
        for (int nt = 0; nt < 8; nt++) {
            int d = nt * 16 + l15;
            float c2v = c2[d];
            #pragma unroll
            for (int r = 0; r < 4; r++) {
                int n = nbase + m * 16 + quad * 4 + r;
                if (n < NN) {
                    size_t idx = (size_t)n * DD + d;
                    out[idx] = hf[idx] + acc2[m][nt][r] + c2v;
                }
            }
        }
    }
}

extern "C" void kernel_launch(void* const* d_in, const int* in_sizes, int n_in,
                              void* d_out, int out_size, void* d_ws, size_t ws_size,
                              hipStream_t stream) {
    const float* h      = (const float*)d_in[0];
    const float* coords = (const float*)d_in[1];
    const int* ei       = (const int*)d_in[2];   // int64 in reference -> int32 from harness
    const float* W1 = (const float*)d_in[3];
    const float* b1 = (const float*)d_in[4];
    const float* W2 = (const float*)d_in[5];
    const float* b2 = (const float*)d_in[6];
    const float* U1 = (const float*)d_in[7];
    const float* c1 = (const float*)d_in[8];
    const float* U2 = (const float*)d_in[9];
    const float* c2 = (const float*)d_in[10];
    float* out = (float*)d_out;

    char* ws = (char*)d_ws;
    float* agg = (float*)ws;                                    // 25,600,000 B, atomically accumulated
    unsigned short* hp = (unsigned short*)(ws + 25600000);      // 12,800,000 B bf16 h
    unsigned short* packs = (unsigned short*)(ws + 38400000);   // 6 * 32768 B packed weights
    const bf16x8* w1a = (const bf16x8*)(packs);
    const bf16x8* w1b = (const bf16x8*)(packs + 16384);
    const bf16x8* w2p = (const bf16x8*)(packs + 32768);
    const bf16x8* u1a = (const bf16x8*)(packs + 49152);
    const bf16x8* u1b = (const bf16x8*)(packs + 65536);
    const bf16x8* u2p = (const bf16x8*)(packs + 81920);

    hipMemsetAsync(agg, 0, (size_t)NN * DD * sizeof(float), stream);
    pack_h_kernel<<<6250, 256, 0, stream>>>(h, hp);
    pack_w_kernel<<<384, 256, 0, stream>>>(W1, W2, U1, U2, packs);
    edge_kernel<<<EE / 256, 256, 0, stream>>>(hp, coords, ei, w1a, w1b, w2p, W1, b1, b2, agg);
    node_kernel<<<(NN + 255) / 256, 256, 0, stream>>>(hp, h, agg, u1a, u1b, u2p, c1, c2, out);
}

// Round 3
// 647.586 us; speedup vs baseline: 1.0250x; 1.0250x over previous
//
#include <hip/hip_runtime.h>
#include <hip/hip_bf16.h>

#define NN 50000
#define EE 800000
#define DD 128

typedef __attribute__((ext_vector_type(8))) short bf16x8;
typedef __attribute__((ext_vector_type(4))) float f32x4;

__device__ __forceinline__ short f2bf(float f) {
    __hip_bfloat16 h = __float2bfloat16(f);
    return __builtin_bit_cast(short, h);
}

__device__ __forceinline__ float fast_silu(float x) {
    return x / (1.0f + __expf(-x));
}

// ---- prep: h (fp32) -> bf16 AND zero agg, 4 elems/thread ----
__global__ void prep_kernel(const float* __restrict__ h, unsigned short* __restrict__ hp,
                            float4* __restrict__ agg4) {
    int t = blockIdx.x * blockDim.x + threadIdx.x;   // 1.6M threads exactly
    float4 v = ((const float4*)h)[t];
    ushort4 o;
    o.x = (unsigned short)f2bf(v.x);
    o.y = (unsigned short)f2bf(v.y);
    o.z = (unsigned short)f2bf(v.z);
    o.w = (unsigned short)f2bf(v.w);
    ((ushort4*)hp)[t] = o;
    agg4[t] = make_float4(0.f, 0.f, 0.f, 0.f);       // 6.4M floats = 1.6M float4 exactly
}

// ---- prep: pack 6 128x128 weight blocks into MFMA B-fragment order ----
// pack[mat][ (nt*4+ks)*64 + lane ][j] = W[n = nt*16 + (lane&15)][k = ks*32 + (lane>>4)*8 + j]
__global__ void pack_w_kernel(const float* __restrict__ W1, const float* __restrict__ W2,
                              const float* __restrict__ U1, const float* __restrict__ U2,
                              unsigned short* __restrict__ packs) {
    int t = blockIdx.x * blockDim.x + threadIdx.x;   // 6*16384 = 98304 exactly
    int mat = t >> 14;
    int r = t & 16383;
    int j = r & 7;
    int lane = (r >> 3) & 63;
    int f = r >> 9;            // 0..31
    int ks = f & 3, nt = f >> 2;
    int n = nt * 16 + (lane & 15);
    int k = ks * 32 + (lane >> 4) * 8 + j;
    float v;
    switch (mat) {
        case 0: v = W1[n * 257 + k];        break;  // W1a (vs h_sender)
        case 1: v = W1[n * 257 + 128 + k];  break;  // W1b (vs h_receiver)
        case 2: v = W2[n * 128 + k];        break;  // W2
        case 3: v = U1[n * 256 + k];        break;  // U1a (vs h)
        case 4: v = U1[n * 256 + 128 + k];  break;  // U1b (vs agg)
        default: v = U2[n * 128 + k];       break;  // U2
    }
    packs[t] = (unsigned short)f2bf(v);
}

// ---- edge kernel: 4 waves/block, 64 edges/wave, pipelined per 16-edge M-tile ----
__global__ __launch_bounds__(256, 4) void edge_kernel(
    const unsigned short* __restrict__ hp,     // bf16 h [NN][128]
    const float* __restrict__ coords,          // [NN][3]
    const int* __restrict__ ei,                // [2][EE] int32
    const bf16x8* __restrict__ w1a_pack,
    const bf16x8* __restrict__ w1b_pack,
    const bf16x8* __restrict__ w2_pack,
    const float* __restrict__ W1raw,           // for w1c = W1[d][256]
    const float* __restrict__ b1,
    const float* __restrict__ b2,
    float* __restrict__ agg)
{
    __shared__ int send_s[4][64];
    __shared__ int recv_s[4][64];
    __shared__ float dist_s[4][64];
    __shared__ unsigned short m1s[4][2][16][136];  // per-wave double buffer, 8.7 KB/wave

    const int tid = threadIdx.x;
    const int wave = tid >> 6, lane = tid & 63;
    const int quad = lane >> 4, l15 = lane & 15;
    const int ebase = blockIdx.x * 256 + wave * 64;

    {
        int e = ebase + lane;
        int s = ei[e];
        int r = ei[EE + e];
        send_s[wave][lane] = s;
        recv_s[wave][lane] = r;
        float dx = coords[3 * s + 0] - coords[3 * r + 0];
        float dy = coords[3 * s + 1] - coords[3 * r + 1];
        float dz = coords[3 * s + 2] - coords[3 * r + 2];
        dist_s[wave][lane] = sqrtf(dx * dx + dy * dy + dz * dz);
    }
    __syncthreads();

    // per-lane d-constants (d = nt*16 + l15), hoisted across all 4 M-tiles
    float w1cv[8], b1v[8];
    #pragma unroll
    for (int nt = 0; nt < 8; nt++) {
        int d = nt * 16 + l15;
        w1cv[nt] = W1raw[d * 257 + 256];
        b1v[nt] = b1[d];
    }

    #pragma unroll
    for (int mt = 0; mt < 4; mt++) {
        const int buf = mt & 1;
        int sr = send_s[wave][mt * 16 + l15];
        int rr = recv_s[wave][mt * 16 + l15];

        bf16x8 a_s[4], a_r[4];
        #pragma unroll
        for (int ks = 0; ks < 4; ks++) {
            a_s[ks] = *(const bf16x8*)(hp + (size_t)sr * DD + ks * 32 + quad * 8);
            a_r[ks] = *(const bf16x8*)(hp + (size_t)rr * DD + ks * 32 + quad * 8);
        }

        // ---- layer 1: acc = Hs*W1a^T + Hr*W1b^T ----
        f32x4 acc[8];
        #pragma unroll
        for (int nt = 0; nt < 8; nt++) acc[nt] = f32x4{0.f, 0.f, 0.f, 0.f};

        #pragma unroll
        for (int ks = 0; ks < 4; ks++) {
            #pragma unroll
            for (int nt = 0; nt < 8; nt++)
                acc[nt] = __builtin_amdgcn_mfma_f32_16x16x32_bf16(
                    a_s[ks], w1a_pack[(nt * 4 + ks) * 64 + lane], acc[nt], 0, 0, 0);
            #pragma unroll
            for (int nt = 0; nt < 8; nt++)
                acc[nt] = __builtin_amdgcn_mfma_f32_16x16x32_bf16(
                    a_r[ks], w1b_pack[(nt * 4 + ks) * 64 + lane], acc[nt], 0, 0, 0);
        }

        // ---- epilogue 1: + dist*w1c + b1, silu, -> LDS (bf16, A-layout rows) ----
        float dd[4];
        #pragma unroll
        for (int r = 0; r < 4; r++) dd[r] = dist_s[wave][mt * 16 + quad * 4 + r];
        #pragma unroll
        for (int nt = 0; nt < 8; nt++) {
            int d = nt * 16 + l15;
            #pragma unroll
            for (int r = 0; r < 4; r++) {
                float pre = acc[nt][r] + dd[r] * w1cv[nt] + b1v[nt];
                m1s[wave][buf][quad * 4 + r][d] = (unsigned short)f2bf(fast_silu(pre));
            }
        }
        asm volatile("s_waitcnt lgkmcnt(0)" ::: "memory");  // wave-internal LDS write->read

        // ---- layer 2: acc2 = M1*W2^T ----
        bf16x8 a2[4];
        #pragma unroll
        for (int ks = 0; ks < 4; ks++)
            a2[ks] = *(const bf16x8*)(&m1s[wave][buf][l15][ks * 32 + quad * 8]);

        f32x4 acc2[8];
        #pragma unroll
        for (int nt = 0; nt < 8; nt++) acc2[nt] = f32x4{0.f, 0.f, 0.f, 0.f};

        #pragma unroll
        for (int ks = 0; ks < 4; ks++)
            #pragma unroll
            for (int nt = 0; nt < 8; nt++)
                acc2[nt] = __builtin_amdgcn_mfma_f32_16x16x32_bf16(
                    a2[ks], w2_pack[(nt * 4 + ks) * 64 + lane], acc2[nt], 0, 0, 0);

        // ---- epilogue 2: silu(acc2 + b2), atomic scatter-add into agg ----
        int rrr[4];
        #pragma unroll
        for (int r = 0; r < 4; r++) rrr[r] = recv_s[wave][mt * 16 + quad * 4 + r];
        #pragma unroll
        for (int nt = 0; nt < 8; nt++) {
            int d = nt * 16 + l15;
            float b2v = b2[d];
            #pragma unroll
            for (int r = 0; r < 4; r++) {
                float v = fast_silu(acc2[nt][r] + b2v);
                unsafeAtomicAdd(&agg[(size_t)rrr[r] * DD + d], v);
            }
        }
    }
}

// ---- node kernel: out = h + U2*silu(U1a*h + U1b*agg + c1) + c2 ----
// 4 waves/block, 16 nodes/wave
__global__ __launch_bounds__(256, 4) void node_kernel(
    const unsigned short* __restrict__ hp,
    const float* __restrict__ hf,
    const float* __restrict__ agg,
    const bf16x8* __restrict__ u1a_pack,
    const bf16x8* __restrict__ u1b_pack,
    const bf16x8* __restrict__ u2_pack,
    const float* __restrict__ c1,
    const float* __restrict__ c2,
    float* __restrict__ out)
{
    __shared__ unsigned short u1s[4][16][136];

    const int tid = threadIdx.x;
    const int wave = tid >> 6, lane = tid & 63;
    const int quad = lane >> 4, l15 = lane & 15;
    const int nbase = blockIdx.x * 64 + wave * 16;

    int n = nbase + l15;
    int nrow = n < NN ? n : NN - 1;

    float c1v[8];
    #pragma unroll
    for (int nt = 0; nt < 8; nt++) c1v[nt] = c1[nt * 16 + l15];

    bf16x8 ah[4], ag[4];
    #pragma unroll
    for (int ks = 0; ks < 4; ks++) {
        ah[ks] = *(const bf16x8*)(hp + (size_t)nrow * DD + ks * 32 + quad * 8);
        const float* ap = agg + (size_t)nrow * DD + ks * 32 + quad * 8;
        f32x4 g0 = *(const f32x4*)ap;
        f32x4 g1 = *(const f32x4*)(ap + 4);
        bf16x8 t;
        t[0] = f2bf(g0[0]); t[1] = f2bf(g0[1]); t[2] = f2bf(g0[2]); t[3] = f2bf(g0[3]);
        t[4] = f2bf(g1[0]); t[5] = f2bf(g1[1]); t[6] = f2bf(g1[2]); t[7] = f2bf(g1[3]);
        ag[ks] = t;
    }

    f32x4 acc[8];
    #pragma unroll
    for (int nt = 0; nt < 8; nt++) acc[nt] = f32x4{0.f, 0.f, 0.f, 0.f};

    #pragma unroll
    for (int ks = 0; ks < 4; ks++) {
        #pragma unroll
        for (int nt = 0; nt < 8; nt++)
            acc[nt] = __builtin_amdgcn_mfma_f32_16x16x32_bf16(
                ah[ks], u1a_pack[(nt * 4 + ks) * 64 + lane], acc[nt], 0, 0, 0);
        #pragma unroll
        for (int nt = 0; nt < 8; nt++)
            acc[nt] = __builtin_amdgcn_mfma_f32_16x16x32_bf16(
                ag[ks], u1b_pack[(nt * 4 + ks) * 64 + lane], acc[nt], 0, 0, 0);
    }

    #pragma unroll
    for (int nt = 0; nt < 8; nt++) {
        int d = nt * 16 + l15;
        #pragma unroll
        for (int r = 0; r < 4; r++) {
            float pre = acc[nt][r] + c1v[nt];
            u1s[wave][quad * 4 + r][d] = (unsigned short)f2bf(fast_silu(pre));
        }
    }
    asm volatile("s_waitcnt lgkmcnt(0)" ::: "memory");

    bf16x8 a2[4];
    #pragma unroll
    for (int ks = 0; ks < 4; ks++)
        a2[ks] = *(const bf16x8*)(&u1s[wave][l15][ks * 32 + quad * 8]);

    f32x4 acc2[8];
    #pragma unroll
    for (int nt = 0; nt < 8; nt++) acc2[nt] = f32x4{0.f, 0.f, 0.f, 0.f};

    #pragma unroll
    for (int ks = 0; ks < 4; ks++)
        #pragma unroll
        for (int nt = 0; nt < 8; nt++)
            acc2[nt] = __builtin_amdgcn_mfma_f32_16x16x32_bf16(
                a2[ks], u2_pack[(nt * 4 + ks) * 64 + lane], acc2[nt], 0, 0, 0);

    #pragma unroll
    for (int nt = 0; nt < 8; nt++) {
        int d = nt * 16 + l15;
        float c2v = c2[d];
        #pragma unroll
        for (int r = 0; r < 4; r++) {
            int n2 = nbase + quad * 4 + r;
            if (n2 < NN) {
                size_t idx = (size_t)n2 * DD + d;
                out[idx] = hf[idx] + acc2[nt][r] + c2v;
            }
        }
    }
}

extern "C" void kernel_launch(void* const* d_in, const int* in_sizes, int n_in,
                              void* d_out, int out_size, void* d_ws, size_t ws_size,
                              hipStream_t stream) {
    const float* h      = (const float*)d_in[0];
    const float* coords = (const float*)d_in[1];
    const int* ei       = (const int*)d_in[2];   // int64 in reference -> int32 from harness
    const float* W1 = (const float*)d_in[3];
    const float* b1 = (const float*)d_in[4];
    const float* W2 = (const float*)d_in[5];
    const float* b2 = (const float*)d_in[6];
    const float* U1 = (const float*)d_in[7];
    const float* c1 = (const float*)d_in[8];
    const float* U2 = (const float*)d_in[9];
    const float* c2 = (const float*)d_in[10];
    float* out = (float*)d_out;

    char* ws = (char*)d_ws;
    float* agg = (float*)ws;                                    // 25,600,000 B
    unsigned short* hp = (unsigned short*)(ws + 25600000);      // 12,800,000 B bf16 h
    unsigned short* packs = (unsigned short*)(ws + 38400000);   // 6 * 32768 B packed weights
    const bf16x8* w1a = (const bf16x8*)(packs);
    const bf16x8* w1b = (const bf16x8*)(packs + 16384);
    const bf16x8* w2p = (const bf16x8*)(packs + 32768);
    const bf16x8* u1a = (const bf16x8*)(packs + 49152);
    const bf16x8* u1b = (const bf16x8*)(packs + 65536);
    const bf16x8* u2p = (const bf16x8*)(packs + 81920);

    prep_kernel<<<6250, 256, 0, stream>>>(h, hp, (float4*)agg);
    pack_w_kernel<<<384, 256, 0, stream>>>(W1, W2, U1, U2, packs);
    edge_kernel<<<EE / 256, 256, 0, stream>>>(hp, coords, ei, w1a, w1b, w2p, W1, b1, b2, agg);
    node_kernel<<<(NN + 63) / 64, 256, 0, stream>>>(hp, h, agg, u1a, u1b, u2p, c1, c2, out);
}

// Round 4
// 510.132 us; speedup vs baseline: 1.3012x; 1.2694x over previous
//
#include <hip/hip_runtime.h>
#include <hip/hip_bf16.h>

#define NN 50000
#define EE 800000
#define DD 128

typedef __attribute__((ext_vector_type(8))) short bf16x8;
typedef __attribute__((ext_vector_type(4))) float f32x4;

__device__ __forceinline__ short f2bf(float f) {
    __hip_bfloat16 h = __float2bfloat16(f);
    return __builtin_bit_cast(short, h);
}

__device__ __forceinline__ float bf2f(short s) {
    unsigned int u = ((unsigned int)(unsigned short)s) << 16;
    return __builtin_bit_cast(float, u);
}

__device__ __forceinline__ float fast_silu(float x) {
    return x / (1.0f + __expf(-x));
}

// ---- prep: h (fp32) -> bf16 AND zero agg, 4 elems/thread ----
__global__ void prep_kernel(const float* __restrict__ h, unsigned short* __restrict__ hp,
                            float4* __restrict__ agg4) {
    int t = blockIdx.x * blockDim.x + threadIdx.x;   // 1.6M threads exactly
    float4 v = ((const float4*)h)[t];
    ushort4 o;
    o.x = (unsigned short)f2bf(v.x);
    o.y = (unsigned short)f2bf(v.y);
    o.z = (unsigned short)f2bf(v.z);
    o.w = (unsigned short)f2bf(v.w);
    ((ushort4*)hp)[t] = o;
    agg4[t] = make_float4(0.f, 0.f, 0.f, 0.f);       // 6.4M floats = 1.6M float4 exactly
}

// ---- prep: pack 6 128x128 weight blocks into MFMA B-fragment order + w1c ----
// pack[mat][ (nt*4+ks)*64 + lane ][j] = W[n = nt*16 + (lane&15)][k = ks*32 + (lane>>4)*8 + j]
__global__ void pack_w_kernel(const float* __restrict__ W1, const float* __restrict__ W2,
                              const float* __restrict__ U1, const float* __restrict__ U2,
                              unsigned short* __restrict__ packs,
                              float* __restrict__ w1c_out) {
    int t = blockIdx.x * blockDim.x + threadIdx.x;   // 385 blocks: 6*16384 pack + 128 w1c
    if (t >= 98304) {
        int d = t - 98304;
        if (d < 128) w1c_out[d] = W1[d * 257 + 256];
        return;
    }
    int mat = t >> 14;
    int r = t & 16383;
    int j = r & 7;
    int lane = (r >> 3) & 63;
    int f = r >> 9;            // 0..31
    int ks = f & 3, nt = f >> 2;
    int n = nt * 16 + (lane & 15);
    int k = ks * 32 + (lane >> 4) * 8 + j;
    float v;
    switch (mat) {
        case 0: v = W1[n * 257 + k];        break;  // W1a (vs h_sender)
        case 1: v = W1[n * 257 + 128 + k];  break;  // W1b (vs h_receiver)
        case 2: v = W2[n * 128 + k];        break;  // W2
        case 3: v = U1[n * 256 + k];        break;  // U1a (vs h)
        case 4: v = U1[n * 256 + 128 + k];  break;  // U1b (vs agg)
        default: v = U2[n * 128 + k];       break;  // U2
    }
    packs[t] = (unsigned short)f2bf(v);
}

// ---- prep_g: per-node G1a = h*W1a^T + b1, G1b = h*W1b^T, stored bf16 [NN][256] ----
__global__ __launch_bounds__(256, 2) void prep_g_kernel(
    const unsigned short* __restrict__ hp,
    const bf16x8* __restrict__ w1a_pack,
    const bf16x8* __restrict__ w1b_pack,
    const float* __restrict__ b1,
    unsigned short* __restrict__ G)
{
    const int tid = threadIdx.x;
    const int wave = tid >> 6, lane = tid & 63;
    const int quad = lane >> 4, l15 = lane & 15;
    const int nbase = blockIdx.x * 64 + wave * 16;

    int n = nbase + l15;
    int nrow = n < NN ? n : NN - 1;

    bf16x8 ah[4];
    #pragma unroll
    for (int ks = 0; ks < 4; ks++)
        ah[ks] = *(const bf16x8*)(hp + (size_t)nrow * DD + ks * 32 + quad * 8);

    f32x4 acca[8], accb[8];
    #pragma unroll
    for (int nt = 0; nt < 8; nt++) {
        acca[nt] = f32x4{0.f, 0.f, 0.f, 0.f};
        accb[nt] = f32x4{0.f, 0.f, 0.f, 0.f};
    }

    #pragma unroll
    for (int ks = 0; ks < 4; ks++) {
        #pragma unroll
        for (int nt = 0; nt < 8; nt++)
            acca[nt] = __builtin_amdgcn_mfma_f32_16x16x32_bf16(
                ah[ks], w1a_pack[(nt * 4 + ks) * 64 + lane], acca[nt], 0, 0, 0);
        #pragma unroll
        for (int nt = 0; nt < 8; nt++)
            accb[nt] = __builtin_amdgcn_mfma_f32_16x16x32_bf16(
                ah[ks], w1b_pack[(nt * 4 + ks) * 64 + lane], accb[nt], 0, 0, 0);
    }

    #pragma unroll
    for (int nt = 0; nt < 8; nt++) {
        int d = nt * 16 + l15;
        float b1v = b1[d];
        #pragma unroll
        for (int r = 0; r < 4; r++) {
            int n2 = nbase + quad * 4 + r;
            if (n2 < NN) {
                G[(size_t)n2 * 256 + d]       = (unsigned short)f2bf(acca[nt][r] + b1v);
                G[(size_t)n2 * 256 + 128 + d] = (unsigned short)f2bf(accb[nt][r]);
            }
        }
    }
}

// ---- edge kernel: gather G slices -> VALU silu (direct A-frag) -> W2 MFMA -> atomics ----
__global__ __launch_bounds__(256, 3) void edge_kernel(
    const unsigned short* __restrict__ G,      // [NN][256] bf16: [G1a+b1 | G1b]
    const float* __restrict__ coords,          // [NN][3]
    const int* __restrict__ ei,                // [2][EE] int32
    const bf16x8* __restrict__ w2_pack,        // 32 KB, L1-resident
    const float* __restrict__ w1c,             // [128] fp32, k-order
    const float* __restrict__ b2,
    float* __restrict__ agg)
{
    __shared__ int send_s[4][64];
    __shared__ int recv_s[4][64];
    __shared__ float dist_s[4][64];

    const int tid = threadIdx.x;
    const int wave = tid >> 6, lane = tid & 63;
    const int quad = lane >> 4, l15 = lane & 15;
    const int ebase = blockIdx.x * 256 + wave * 64;

    {
        int e = ebase + lane;
        int s = ei[e];
        int r = ei[EE + e];
        send_s[wave][lane] = s;
        recv_s[wave][lane] = r;
        float dx = coords[3 * s + 0] - coords[3 * r + 0];
        float dy = coords[3 * s + 1] - coords[3 * r + 1];
        float dz = coords[3 * s + 2] - coords[3 * r + 2];
        dist_s[wave][lane] = sqrtf(dx * dx + dy * dy + dz * dz);
    }
    __syncthreads();

    // per-lane constants: w1c at k = ks*32 + quad*8 + j (this lane's A-frag k-range)
    float w1cf[4][8];
    #pragma unroll
    for (int ks = 0; ks < 4; ks++) {
        f32x4 c0 = *(const f32x4*)(w1c + ks * 32 + quad * 8);
        f32x4 c1 = *(const f32x4*)(w1c + ks * 32 + quad * 8 + 4);
        #pragma unroll
        for (int j = 0; j < 4; j++) { w1cf[ks][j] = c0[j]; w1cf[ks][4 + j] = c1[j]; }
    }
    float b2f[8];
    #pragma unroll
    for (int nt = 0; nt < 8; nt++) b2f[nt] = b2[nt * 16 + l15];

    // tile-0 gathers (nontemporal: don't evict W2 from L1)
    bf16x8 ga[4], gb[4];
    {
        int sr = send_s[wave][l15], rr = recv_s[wave][l15];
        #pragma unroll
        for (int ks = 0; ks < 4; ks++) {
            ga[ks] = __builtin_nontemporal_load(
                (const bf16x8*)(G + (size_t)sr * 256 + ks * 32 + quad * 8));
            gb[ks] = __builtin_nontemporal_load(
                (const bf16x8*)(G + (size_t)rr * 256 + 128 + ks * 32 + quad * 8));
        }
    }

    #pragma unroll
    for (int mt = 0; mt < 4; mt++) {
        float dist = dist_s[wave][mt * 16 + l15];   // lane l15 = edge row in A-layout

        // layer-1 epilogue in registers, directly in A-fragment layout
        bf16x8 m1f[4];
        #pragma unroll
        for (int ks = 0; ks < 4; ks++) {
            #pragma unroll
            for (int j = 0; j < 8; j++) {
                float pre = bf2f(ga[ks][j]) + bf2f(gb[ks][j]) + dist * w1cf[ks][j];
                m1f[ks][j] = f2bf(fast_silu(pre));
            }
        }

        // prefetch next tile's gathers BEFORE issuing this tile's atomics
        if (mt < 3) {
            int sr2 = send_s[wave][(mt + 1) * 16 + l15];
            int rr2 = recv_s[wave][(mt + 1) * 16 + l15];
            #pragma unroll
            for (int ks = 0; ks < 4; ks++) {
                ga[ks] = __builtin_nontemporal_load(
                    (const bf16x8*)(G + (size_t)sr2 * 256 + ks * 32 + quad * 8));
                gb[ks] = __builtin_nontemporal_load(
                    (const bf16x8*)(G + (size_t)rr2 * 256 + 128 + ks * 32 + quad * 8));
            }
        }

        // layer 2: acc2 = M1 * W2^T   (W2 frags from L1)
        f32x4 acc2[8];
        #pragma unroll
        for (int nt = 0; nt < 8; nt++) acc2[nt] = f32x4{0.f, 0.f, 0.f, 0.f};
        #pragma unroll
        for (int ks = 0; ks < 4; ks++)
            #pragma unroll
            for (int nt = 0; nt < 8; nt++)
                acc2[nt] = __builtin_amdgcn_mfma_f32_16x16x32_bf16(
                    m1f[ks], w2_pack[(nt * 4 + ks) * 64 + lane], acc2[nt], 0, 0, 0);

        // epilogue 2: silu(acc2 + b2), atomic scatter-add (C-layout: row=quad*4+r)
        int rrr[4];
        #pragma unroll
        for (int r = 0; r < 4; r++) rrr[r] = recv_s[wave][mt * 16 + quad * 4 + r];
        #pragma unroll
        for (int nt = 0; nt < 8; nt++) {
            #pragma unroll
            for (int r = 0; r < 4; r++) {
                float v = fast_silu(acc2[nt][r] + b2f[nt]);
                unsafeAtomicAdd(&agg[(size_t)rrr[r] * DD + nt * 16 + l15], v);
            }
        }
    }
}

// ---- node kernel: out = h + U2*silu(U1a*h + U1b*agg + c1) + c2 ----
__global__ __launch_bounds__(256, 4) void node_kernel(
    const unsigned short* __restrict__ hp,
    const float* __restrict__ hf,
    const float* __restrict__ agg,
    const bf16x8* __restrict__ u1a_pack,
    const bf16x8* __restrict__ u1b_pack,
    const bf16x8* __restrict__ u2_pack,
    const float* __restrict__ c1,
    const float* __restrict__ c2,
    float* __restrict__ out)
{
    __shared__ unsigned short u1s[4][16][136];

    const int tid = threadIdx.x;
    const int wave = tid >> 6, lane = tid & 63;
    const int quad = lane >> 4, l15 = lane & 15;
    const int nbase = blockIdx.x * 64 + wave * 16;

    int n = nbase + l15;
    int nrow = n < NN ? n : NN - 1;

    float c1v[8];
    #pragma unroll
    for (int nt = 0; nt < 8; nt++) c1v[nt] = c1[nt * 16 + l15];

    bf16x8 ah[4], ag[4];
    #pragma unroll
    for (int ks = 0; ks < 4; ks++) {
        ah[ks] = *(const bf16x8*)(hp + (size_t)nrow * DD + ks * 32 + quad * 8);
        const float* ap = agg + (size_t)nrow * DD + ks * 32 + quad * 8;
        f32x4 g0 = *(const f32x4*)ap;
        f32x4 g1 = *(const f32x4*)(ap + 4);
        bf16x8 t;
        t[0] = f2bf(g0[0]); t[1] = f2bf(g0[1]); t[2] = f2bf(g0[2]); t[3] = f2bf(g0[3]);
        t[4] = f2bf(g1[0]); t[5] = f2bf(g1[1]); t[6] = f2bf(g1[2]); t[7] = f2bf(g1[3]);
        ag[ks] = t;
    }

    f32x4 acc[8];
    #pragma unroll
    for (int nt = 0; nt < 8; nt++) acc[nt] = f32x4{0.f, 0.f, 0.f, 0.f};

    #pragma unroll
    for (int ks = 0; ks < 4; ks++) {
        #pragma unroll
        for (int nt = 0; nt < 8; nt++)
            acc[nt] = __builtin_amdgcn_mfma_f32_16x16x32_bf16(
                ah[ks], u1a_pack[(nt * 4 + ks) * 64 + lane], acc[nt], 0, 0, 0);
        #pragma unroll
        for (int nt = 0; nt < 8; nt++)
            acc[nt] = __builtin_amdgcn_mfma_f32_16x16x32_bf16(
                ag[ks], u1b_pack[(nt * 4 + ks) * 64 + lane], acc[nt], 0, 0, 0);
    }

    #pragma unroll
    for (int nt = 0; nt < 8; nt++) {
        int d = nt * 16 + l15;
        #pragma unroll
        for (int r = 0; r < 4; r++) {
            float pre = acc[nt][r] + c1v[nt];
            u1s[wave][quad * 4 + r][d] = (unsigned short)f2bf(fast_silu(pre));
        }
    }
    asm volatile("s_waitcnt lgkmcnt(0)" ::: "memory");

    bf16x8 a2[4];
    #pragma unroll
    for (int ks = 0; ks < 4; ks++)
        a2[ks] = *(const bf16x8*)(&u1s[wave][l15][ks * 32 + quad * 8]);

    f32x4 acc2[8];
    #pragma unroll
    for (int nt = 0; nt < 8; nt++) acc2[nt] = f32x4{0.f, 0.f, 0.f, 0.f};

    #pragma unroll
    for (int ks = 0; ks < 4; ks++)
        #pragma unroll
        for (int nt = 0; nt < 8; nt++)
            acc2[nt] = __builtin_amdgcn_mfma_f32_16x16x32_bf16(
                a2[ks], u2_pack[(nt * 4 + ks) * 64 + lane], acc2[nt], 0, 0, 0);

    #pragma unroll
    for (int nt = 0; nt < 8; nt++) {
        int d = nt * 16 + l15;
        float c2v = c2[d];
        #pragma unroll
        for (int r = 0; r < 4; r++) {
            int n2 = nbase + quad * 4 + r;
            if (n2 < NN) {
                size_t idx = (size_t)n2 * DD + d;
                out[idx] = hf[idx] + acc2[nt][r] + c2v;
            }
        }
    }
}

extern "C" void kernel_launch(void* const* d_in, const int* in_sizes, int n_in,
                              void* d_out, int out_size, void* d_ws, size_t ws_size,
                              hipStream_t stream) {
    const float* h      = (const float*)d_in[0];
    const float* coords = (const float*)d_in[1];
    const int* ei       = (const int*)d_in[2];   // int64 in reference -> int32 from harness
    const float* W1 = (const float*)d_in[3];
    const float* b1 = (const float*)d_in[4];
    const float* W2 = (const float*)d_in[5];
    const float* b2 = (const float*)d_in[6];
    const float* U1 = (const float*)d_in[7];
    const float* c1 = (const float*)d_in[8];
    const float* U2 = (const float*)d_in[9];
    const float* c2 = (const float*)d_in[10];
    float* out = (float*)d_out;

    char* ws = (char*)d_ws;
    float* agg = (float*)ws;                                    // 25,600,000 B
    unsigned short* hp = (unsigned short*)(ws + 25600000);      // 12,800,000 B bf16 h
    unsigned short* packs = (unsigned short*)(ws + 38400000);   // 196,608 B packed weights
    float* w1c = (float*)(ws + 38600000);                       // 512 B
    unsigned short* G = (unsigned short*)(ws + 38700000);       // 25,600,000 B bf16 [NN][256]
    const bf16x8* w1a = (const bf16x8*)(packs);
    const bf16x8* w1b = (const bf16x8*)(packs + 16384);
    const bf16x8* w2p = (const bf16x8*)(packs + 32768);
    const bf16x8* u1a = (const bf16x8*)(packs + 49152);
    const bf16x8* u1b = (const bf16x8*)(packs + 65536);
    const bf16x8* u2p = (const bf16x8*)(packs + 81920);

    prep_kernel<<<6250, 256, 0, stream>>>(h, hp, (float4*)agg);
    pack_w_kernel<<<385, 256, 0, stream>>>(W1, W2, U1, U2, packs, w1c);
    prep_g_kernel<<<(NN + 63) / 64, 256, 0, stream>>>(hp, w1a, w1b, b1, G);
    edge_kernel<<<EE / 256, 256, 0, stream>>>(G, coords, ei, w2p, w1c, b2, agg);
    node_kernel<<<(NN + 63) / 64, 256, 0, stream>>>(hp, h, agg, u1a, u1b, u2p, c1, c2, out);
}